// Round 1
// baseline (1202.682 us; speedup 1.0000x reference)
//
#include <hip/hip_runtime.h>
#include <math.h>

#define NB 16
#define NT 9
#define PLANE 65536          // 256*256
#define KAP_B 589824         // 9*PLANE  (per-batch kappa elems)
#define M_B   1179648        // 2*KAP_B
#define H_B   2359296        // 4*KAP_B

// d_out layout (floats): [0,16) x_out | [16, +9437184) kappa | then m (18874368) | then H (37748736)
#define OUT_KAP 16
#define OUT_M   9437200
#define OUT_H   28311568

__device__ __forceinline__ float sp10(float x) {
  float z = 10.0f * x;
  return (fmaxf(z, 0.0f) + log1pf(__expf(-fabsf(z)))) * 0.1f;
}

// ---------------- transpose: xg[b,t,xx,yy] = x[b,t,yy,xx] ----------------
__global__ __launch_bounds__(1024) void transpose_kernel(const float* __restrict__ x,
                                                         float* __restrict__ xg) {
  __shared__ float t_[32][33];
  const int plane = blockIdx.z;                 // b*9+t
  const float* src = x + (size_t)plane * PLANE;
  float* dst = xg + (size_t)plane * PLANE;
  const int x0 = blockIdx.x * 32, y0 = blockIdx.y * 32;
  t_[threadIdx.y][threadIdx.x] = src[(y0 + threadIdx.y) * 256 + x0 + threadIdx.x];
  __syncthreads();
  dst[(x0 + threadIdx.y) * 256 + (y0 + threadIdx.x)] = t_[threadIdx.x][threadIdx.y];
}

// ---------------- generic 3x3 SAME conv, optional relu on input ----------------
template <int IC, int OC, bool RELU_IN>
__global__ __launch_bounds__(256) void conv3x3_kernel(const float* __restrict__ in,
                                                      const float* __restrict__ wt,
                                                      float* __restrict__ out) {
  __shared__ float tile[IC][18][18];
  const int b = blockIdx.z;
  const int x0 = blockIdx.x * 16, y0 = blockIdx.y * 16;
  const int tx = threadIdx.x, ty = threadIdx.y;
  const int tid = ty * 16 + tx;
  const float* inb = in + (size_t)b * IC * PLANE;
  for (int idx = tid; idx < IC * 324; idx += 256) {
    int ic = idx / 324;
    int rem = idx % 324;
    int r = rem / 18, c = rem % 18;
    int gy = y0 + r - 1, gx = x0 + c - 1;
    float v = 0.f;
    if (gy >= 0 && gy < 256 && gx >= 0 && gx < 256) {
      v = inb[ic * PLANE + gy * 256 + gx];
      if (RELU_IN) v = fmaxf(v, 0.f);
    }
    tile[ic][r][c] = v;
  }
  __syncthreads();
  float acc[OC];
#pragma unroll
  for (int oc = 0; oc < OC; ++oc) acc[oc] = 0.f;
  for (int ic = 0; ic < IC; ++ic) {
    float v00 = tile[ic][ty + 0][tx + 0], v01 = tile[ic][ty + 0][tx + 1], v02 = tile[ic][ty + 0][tx + 2];
    float v10 = tile[ic][ty + 1][tx + 0], v11 = tile[ic][ty + 1][tx + 1], v12 = tile[ic][ty + 1][tx + 2];
    float v20 = tile[ic][ty + 2][tx + 0], v21 = tile[ic][ty + 2][tx + 1], v22 = tile[ic][ty + 2][tx + 2];
    const float* wp = wt + ic * 9;
#pragma unroll
    for (int oc = 0; oc < OC; ++oc) {
      const float* w9 = wp + oc * IC * 9;
      acc[oc] += v00 * w9[0] + v01 * w9[1] + v02 * w9[2]
               + v10 * w9[3] + v11 * w9[4] + v12 * w9[5]
               + v20 * w9[6] + v21 * w9[7] + v22 * w9[8];
    }
  }
  float* outb = out + ((size_t)b * OC) * PLANE + (y0 + ty) * 256 + (x0 + tx);
#pragma unroll
  for (int oc = 0; oc < OC; ++oc) outb[oc * PLANE] = acc[oc];
}

// ---------------- conv3 (20->54, no relu) with fused output epilogue ----------------
__global__ __launch_bounds__(256) void conv3_fused(const float* __restrict__ in,
                                                   const float* __restrict__ wt,
                                                   float* __restrict__ out_kap,
                                                   float* __restrict__ out_m,
                                                   float* __restrict__ out_H) {
  __shared__ float tile[20][18][18];
  const int b = blockIdx.z;
  const int x0 = blockIdx.x * 16, y0 = blockIdx.y * 16;
  const int tx = threadIdx.x, ty = threadIdx.y;
  const int tid = ty * 16 + tx;
  const float* inb = in + (size_t)b * 20 * PLANE;
  for (int idx = tid; idx < 20 * 324; idx += 256) {
    int ic = idx / 324;
    int rem = idx % 324;
    int r = rem / 18, c = rem % 18;
    int gy = y0 + r - 1, gx = x0 + c - 1;
    float v = 0.f;
    if (gy >= 0 && gy < 256 && gx >= 0 && gx < 256)
      v = inb[ic * PLANE + gy * 256 + gx];
    tile[ic][r][c] = v;
  }
  __syncthreads();
  float acc[54];
#pragma unroll
  for (int oc = 0; oc < 54; ++oc) acc[oc] = 0.f;
  for (int ic = 0; ic < 20; ++ic) {
    float v00 = tile[ic][ty + 0][tx + 0], v01 = tile[ic][ty + 0][tx + 1], v02 = tile[ic][ty + 0][tx + 2];
    float v10 = tile[ic][ty + 1][tx + 0], v11 = tile[ic][ty + 1][tx + 1], v12 = tile[ic][ty + 1][tx + 2];
    float v20 = tile[ic][ty + 2][tx + 0], v21 = tile[ic][ty + 2][tx + 1], v22 = tile[ic][ty + 2][tx + 2];
    const float* wp = wt + ic * 9;
#pragma unroll
    for (int oc = 0; oc < 54; ++oc) {
      const float* w9 = wp + oc * 20 * 9;
      acc[oc] += v00 * w9[0] + v01 * w9[1] + v02 * w9[2]
               + v10 * w9[3] + v11 * w9[4] + v12 * w9[5]
               + v20 * w9[6] + v21 * w9[7] + v22 * w9[8];
    }
  }
  const int n = (y0 + ty) * 256 + (x0 + tx);
  // kappa: natural layout, == sp10(p[ch 0..8])
  float* kapb = out_kap + (size_t)b * KAP_B;
#pragma unroll
  for (int t = 0; t < 9; ++t) kapb[t * PLANE + n] = sp10(acc[t]);
  // m: natural layout, == p[ch 9..26]
  float* mb = out_m + (size_t)b * M_B;
#pragma unroll
  for (int c = 0; c < 18; ++c) mb[c * PLANE + n] = acc[9 + c];
  // H: per (i,j) plane, flat index n*9+t
  float* hb = out_H + (size_t)b * H_B + (size_t)n * 9;
#pragma unroll
  for (int t = 0; t < 9; ++t) {
    float g = sp10(acc[27 + t]);
    float vx = acc[36 + t], vy = acc[45 + t];
    hb[t] = g + vx * vx;
    hb[KAP_B + t] = vx * vy;
    hb[2 * KAP_B + t] = vx * vy;
    hb[3 * KAP_B + t] = g + vy * vy;
  }
}

// ---------------- M operator: r = u + kap^2*u + m1*dx + m2*dy - (h11*dxx + 2*h12*dxy + h22*dyy)
// FINAL=false: write w. FINAL=true: compute v, accumulate x_out.
template <bool FINAL>
__global__ __launch_bounds__(256) void m_kernel(const float* __restrict__ u_in,
                                                const float* __restrict__ dout,
                                                const float* __restrict__ xg,
                                                float* __restrict__ w_out,
                                                float* __restrict__ xsum) {
  __shared__ float u[9][18][18];
  __shared__ float red[256];
  const int b = blockIdx.z;
  const int X0 = blockIdx.y * 16;  // xx tile
  const int Y0 = blockIdx.x * 16;  // yy tile
  const int tx = threadIdx.x, ty = threadIdx.y;
  const int tid = ty * 16 + tx;
  const float* ub = u_in + (size_t)b * 9 * PLANE;
  for (int idx = tid; idx < 9 * 324; idx += 256) {
    int t = idx / 324;
    int rem = idx % 324;
    int r = rem / 18, c = rem % 18;
    int xx = X0 + r - 1, yy = Y0 + c - 1;
    float v = 0.f;
    if (xx >= 0 && xx < 256 && yy >= 0 && yy < 256)
      v = ub[t * PLANE + xx * 256 + yy];
    u[t][r][c] = v;
  }
  __syncthreads();
  const int xx = X0 + ty, yy = Y0 + tx;
  const int n = xx * 256 + yy;
  const float* kapb = dout + OUT_KAP + (size_t)b * KAP_B + (size_t)n * 9;
  const float* mb   = dout + OUT_M + (size_t)b * M_B + (size_t)n * 9;
  const float* hbb  = dout + OUT_H + (size_t)b * H_B + (size_t)n * 9;
  float csum = 0.f;
#pragma unroll
  for (int t = 0; t < 9; ++t) {
    float uc = u[t][ty + 1][tx + 1];
    float xp = u[t][ty + 2][tx + 1], xm = u[t][ty + 0][tx + 1];
    float yp = u[t][ty + 1][tx + 2], ym = u[t][ty + 1][tx + 0];
    float xpyp = u[t][ty + 2][tx + 2], xpym = u[t][ty + 2][tx + 0];
    float xmyp = u[t][ty + 0][tx + 2], xmym = u[t][ty + 0][tx + 0];
    float dx = 0.5f * (xp - xm), dy = 0.5f * (yp - ym);
    float dxx = xp - 2.f * uc + xm, dyy = yp - 2.f * uc + ym;
    float dxy = 0.25f * (xpyp - xpym - xmyp + xmym);
    float kap = kapb[t];
    float m1 = mb[t], m2 = mb[KAP_B + t];
    float h11 = hbb[t], h12 = hbb[KAP_B + t], h22 = hbb[3 * KAP_B + t];
    float r = uc + kap * kap * uc + m1 * dx + m2 * dy
            - (h11 * dxx + 2.f * h12 * dxy + h22 * dyy);
    if (!FINAL) {
      w_out[((size_t)(b * 9 + t)) * PLANE + n] = r;
    } else {
      float xgv = xg[((size_t)(b * 9 + t)) * PLANE + n];
      float q = r;
      if (t > 0) q -= u[t - 1][ty + 1][tx + 1];
      if (t < 8) q -= u[t + 1][ty + 1][tx + 1];
      if (t > 0 && t < 8) q += xgv;
      csum += xgv * q;
    }
  }
  if (FINAL) {
    red[tid] = csum;
    __syncthreads();
    for (int s = 128; s > 0; s >>= 1) {
      if (tid < s) red[tid] += red[tid + s];
      __syncthreads();
    }
    if (tid == 0) atomicAdd(xsum + b, red[0]);
  }
}

extern "C" void kernel_launch(void* const* d_in, const int* in_sizes, int n_in,
                              void* d_out, int out_size, void* d_ws, size_t ws_size,
                              hipStream_t stream) {
  const float* x  = (const float*)d_in[0];
  // d_in[1]=kappa, d_in[2]=m, d_in[3]=H are unused by the reference (shadowed).
  const float* w1 = (const float*)d_in[4];
  const float* w2 = (const float*)d_in[5];
  const float* w3 = (const float*)d_in[6];
  float* out = (float*)d_out;
  float* ws = (float*)d_ws;

  float* xg = ws;                     // 9,437,184 floats
  float* p1 = ws + 9437184;           // 10,485,760 floats
  float* p2 = ws + 19922944;          // 20,971,520 floats
  float* wbuf = ws + 9437184;         // reuses p1 (dead after conv2); fits (9.4M <= 10.5M)

  // zero the x_out accumulator region (first 16 floats)
  hipMemsetAsync(d_out, 0, 16 * sizeof(float), stream);

  transpose_kernel<<<dim3(8, 8, NB * NT), dim3(32, 32), 0, stream>>>(x, xg);
  conv3x3_kernel<9, 10, true><<<dim3(16, 16, NB), dim3(16, 16), 0, stream>>>(x, w1, p1);
  conv3x3_kernel<10, 20, true><<<dim3(16, 16, NB), dim3(16, 16), 0, stream>>>(p1, w2, p2);
  conv3_fused<<<dim3(16, 16, NB), dim3(16, 16), 0, stream>>>(p2, w3,
                                                             out + OUT_KAP, out + OUT_M, out + OUT_H);
  m_kernel<false><<<dim3(16, 16, NB), dim3(16, 16), 0, stream>>>(xg, out, nullptr, wbuf, nullptr);
  m_kernel<true><<<dim3(16, 16, NB), dim3(16, 16), 0, stream>>>(wbuf, out, xg, nullptr, out);
}